// Round 1
// baseline (764.376 us; speedup 1.0000x reference)
//
#include <hip/hip_runtime.h>
#include <math.h>

// PruningAgent: encoder(2 Linear+ReLU) -> 2x GCNConv -> policy/value heads.
// Layer graph N=40000,E=640000; 8 head graphs batched as one 65536-node graph.
// Strategy r0: fp32 everywhere (tiny logits -> head_mask knife-edge forbids bf16),
// device-built CSR (histogram+scan+fill) so aggregation is a coalesced gather
// (one wave per node, float2 per lane) instead of 432M float atomics.

constexpr int N_L  = 40000;
constexpr int E_L  = 640000;
constexpr int F_IN = 256;
constexpr int H_   = 128;
constexpr int L_H  = 8;
constexpr int N_H1 = 8192;
constexpr int E_H1 = 131072;
constexpr int N_HT = 65536;   // 8*8192
constexpr int E_HT = 1048576; // 8*131072

// ---------------- degree / CSR build ----------------

__global__ __launch_bounds__(256) void count_deg_l(const int* __restrict__ ei,
                                                   int* __restrict__ indeg) {
  int i = blockIdx.x * 256 + threadIdx.x;
  if (i < E_L) atomicAdd(&indeg[ei[E_L + i]], 1);
}

__global__ __launch_bounds__(256) void count_deg_h(const int* __restrict__ hei,
                                                   int* __restrict__ indeg) {
  int i = blockIdx.x * 256 + threadIdx.x;
  if (i < E_HT) {
    int l = i >> 17, e = i & (E_H1 - 1);
    atomicAdd(&indeg[l * N_H1 + hei[l * 2 * E_H1 + E_H1 + e]], 1);
  }
}

__global__ __launch_bounds__(256) void dinv_kernel(const int* __restrict__ indeg,
                                                   float* __restrict__ dinv, int n) {
  int i = blockIdx.x * 256 + threadIdx.x;
  if (i < n) dinv[i] = 1.0f / sqrtf((float)(indeg[i] + 1)); // +1 = self loop
}

// block-level inclusive scan -> exclusive out + block sums
__global__ __launch_bounds__(1024) void scan_block(const int* __restrict__ in, int n,
                                                   int* __restrict__ out,
                                                   int* __restrict__ bsum) {
  __shared__ int s[1024];
  int t = threadIdx.x;
  int i = blockIdx.x * 1024 + t;
  int v = (i < n) ? in[i] : 0;
  s[t] = v;
  __syncthreads();
  for (int off = 1; off < 1024; off <<= 1) {
    int x = (t >= off) ? s[t - off] : 0;
    __syncthreads();
    s[t] += x;
    __syncthreads();
  }
  if (i < n) out[i] = s[t] - v;     // exclusive
  if (t == 1023) bsum[blockIdx.x] = s[t];
}

// single wave: exclusive scan of <=64 block sums, total stored at bsum[nb]
__global__ __launch_bounds__(64) void scan_top(int* __restrict__ bsum, int nb) {
  int lane = threadIdx.x;
  int v = (lane < nb) ? bsum[lane] : 0;
  int incl = v;
  for (int off = 1; off < 64; off <<= 1) {
    int x = __shfl_up(incl, off);
    if (lane >= off) incl += x;
  }
  int total = __shfl(incl, 63);
  if (lane < nb) bsum[lane] = incl - v;
  if (lane == 0) bsum[nb] = total;
}

__global__ __launch_bounds__(256) void scan_fix(int* __restrict__ rowptr,
                                                const int* __restrict__ bsum,
                                                int n, int nb,
                                                int* __restrict__ rowpos) {
  int i = blockIdx.x * 256 + threadIdx.x;
  if (i < n) {
    int v = rowptr[i] + bsum[i >> 10];
    rowptr[i] = v;
    rowpos[i] = v;
  } else if (i == n) {
    rowptr[n] = bsum[nb];
  }
}

__global__ __launch_bounds__(256) void fill_csr_l(const int* __restrict__ ei,
                                                  int* __restrict__ rowpos,
                                                  int* __restrict__ col) {
  int i = blockIdx.x * 256 + threadIdx.x;
  if (i < E_L) {
    int dst = ei[E_L + i];
    int p = atomicAdd(&rowpos[dst], 1);
    col[p] = ei[i];
  }
}

__global__ __launch_bounds__(256) void fill_csr_h(const int* __restrict__ hei,
                                                  int* __restrict__ rowpos,
                                                  int* __restrict__ col) {
  int i = blockIdx.x * 256 + threadIdx.x;
  if (i < E_HT) {
    int l = i >> 17, e = i & (E_H1 - 1);
    int base = l * 2 * E_H1;
    int dst = l * N_H1 + hei[base + E_H1 + e];
    int src = l * N_H1 + hei[base + e];
    int p = atomicAdd(&rowpos[dst], 1);
    col[p] = src;
  }
}

// ---------------- fp32 matmul: C[M,128] = act(A[M,K] @ W[K,128] + b) ----------------
// 256 thr/block, 64-row tile, K-chunks of 32. As stored transposed [k][row].

template <int K, bool RELU, bool BIAS>
__global__ __launch_bounds__(256) void mm_kernel(const float* __restrict__ A,
                                                 const float* __restrict__ W,
                                                 const float* __restrict__ bias,
                                                 float* __restrict__ C, int M) {
  __shared__ float As[32][68];   // stride 68 floats = 272B -> float4-aligned rows
  __shared__ float Ws[32][128];
  const int tid = threadIdx.x;
  const int m0 = blockIdx.x * 64;
  const int cb = (tid & 31) * 4;  // col base (0..124)
  const int rb = (tid >> 5) * 8;  // row base (0..56)
  float acc[8][4] = {};

  for (int kc = 0; kc < K; kc += 32) {
    __syncthreads();
    // A chunk: 64 rows x 32 k -> 512 float4, 2 per thread (coalesced)
#pragma unroll
    for (int i = 0; i < 2; ++i) {
      int f = tid + 256 * i;         // float4 id
      int row = f >> 3;
      int k4 = (f & 7) * 4;
      float4 av = *(const float4*)(A + (size_t)(m0 + row) * K + kc + k4);
      As[k4 + 0][row] = av.x;
      As[k4 + 1][row] = av.y;
      As[k4 + 2][row] = av.z;
      As[k4 + 3][row] = av.w;
    }
    // W chunk: 32 rows x 128 cols -> 1024 float4, 4 per thread
#pragma unroll
    for (int i = 0; i < 4; ++i) {
      int f = tid + 256 * i;
      int row = f >> 5;
      int c4 = (f & 31) * 4;
      *(float4*)&Ws[row][c4] = *(const float4*)(W + (size_t)(kc + row) * H_ + c4);
    }
    __syncthreads();
#pragma unroll
    for (int kk = 0; kk < 32; ++kk) {
      float4 a0 = *(const float4*)&As[kk][rb];
      float4 a1 = *(const float4*)&As[kk][rb + 4];
      float4 wv = *(const float4*)&Ws[kk][cb];
      float ar[8] = {a0.x, a0.y, a0.z, a0.w, a1.x, a1.y, a1.z, a1.w};
      float wr[4] = {wv.x, wv.y, wv.z, wv.w};
#pragma unroll
      for (int r = 0; r < 8; ++r)
#pragma unroll
        for (int c = 0; c < 4; ++c)
          acc[r][c] = fmaf(ar[r], wr[c], acc[r][c]);
    }
  }

  float4 bv = make_float4(0.f, 0.f, 0.f, 0.f);
  if (BIAS) bv = *(const float4*)(bias + cb);
#pragma unroll
  for (int r = 0; r < 8; ++r) {
    float4 o;
    o.x = acc[r][0] + bv.x;
    o.y = acc[r][1] + bv.y;
    o.z = acc[r][2] + bv.z;
    o.w = acc[r][3] + bv.w;
    if (RELU) {
      o.x = fmaxf(o.x, 0.f); o.y = fmaxf(o.y, 0.f);
      o.z = fmaxf(o.z, 0.f); o.w = fmaxf(o.w, 0.f);
    }
    *(float4*)(C + (size_t)(m0 + rb + r) * H_ + cb) = o;
  }
}

// ---------------- GCN aggregation (gather form) ----------------
// out[v] = relu( dinv[v]^2*h[v] + sum_{u->v} dinv[u]dinv[v] h[u] + b )
// one wave per node, lane = float2 feature pair (128 feats / 64 lanes).

__global__ __launch_bounds__(256) void agg_kernel(const float* __restrict__ Hin,
                                                  const float* __restrict__ dinv,
                                                  const int* __restrict__ rowptr,
                                                  const int* __restrict__ col,
                                                  const float* __restrict__ bias,
                                                  float* __restrict__ Hout, int n) {
  int v = blockIdx.x * 4 + (threadIdx.x >> 6);
  if (v >= n) return;
  int lane = threadIdx.x & 63;
  const float2* H2 = (const float2*)Hin;
  float dv = dinv[v];
  float2 acc = H2[(size_t)v * 64 + lane];
  acc.x *= dv * dv;
  acc.y *= dv * dv;
  int e = rowptr[v], e1 = rowptr[v + 1];
  for (; e + 4 <= e1; e += 4) {  // 4 loads in flight
    int u0 = col[e], u1 = col[e + 1], u2 = col[e + 2], u3 = col[e + 3];
    float c0 = dinv[u0] * dv, c1 = dinv[u1] * dv, c2 = dinv[u2] * dv, c3 = dinv[u3] * dv;
    float2 x0 = H2[(size_t)u0 * 64 + lane];
    float2 x1 = H2[(size_t)u1 * 64 + lane];
    float2 x2 = H2[(size_t)u2 * 64 + lane];
    float2 x3 = H2[(size_t)u3 * 64 + lane];
    acc.x += x0.x * c0 + x1.x * c1 + x2.x * c2 + x3.x * c3;
    acc.y += x0.y * c0 + x1.y * c1 + x2.y * c2 + x3.y * c3;
  }
  for (; e < e1; ++e) {
    int u = col[e];
    float c = dinv[u] * dv;
    float2 x = H2[(size_t)u * 64 + lane];
    acc.x += x.x * c;
    acc.y += x.y * c;
  }
  float2 b2 = ((const float2*)bias)[lane];
  acc.x = fmaxf(acc.x + b2.x, 0.f);
  acc.y = fmaxf(acc.y + b2.y, 0.f);
  ((float2*)Hout)[(size_t)v * 64 + lane] = acc;
}

// ---------------- heads ----------------
// out[i] = sigmoid( dot(Hrelu[i], w2) + b2 ); one wave per row.
__global__ __launch_bounds__(256) void prob_kernel(const float* __restrict__ Hrelu,
                                                   const float* __restrict__ w2,
                                                   const float* __restrict__ b2,
                                                   float* __restrict__ out, int n) {
  int r = blockIdx.x * 4 + (threadIdx.x >> 6);
  if (r >= n) return;
  int lane = threadIdx.x & 63;
  float2 h = ((const float2*)Hrelu)[(size_t)r * 64 + lane];
  float2 w = ((const float2*)w2)[lane];
  float p = h.x * w.x + h.y * w.y;
  for (int off = 32; off; off >>= 1) p += __shfl_down(p, off);
  if (lane == 0) out[r] = 1.0f / (1.0f + expf(-(p + b2[0])));
}

__global__ __launch_bounds__(128) void colsum_kernel(const float* __restrict__ H,
                                                     float* __restrict__ hsum, int n) {
  int f = threadIdx.x;
  int r0 = blockIdx.x * 128;
  int r1 = min(r0 + 128, n);
  float acc = 0.f;
  for (int r = r0; r < r1; ++r) acc += H[(size_t)r * 128 + f];
  atomicAdd(&hsum[f], acc);
}

__global__ __launch_bounds__(128) void value_kernel(const float* __restrict__ hsum,
                                                    const float* __restrict__ w1,
                                                    const float* __restrict__ b1,
                                                    const float* __restrict__ w2,
                                                    const float* __restrict__ b2,
                                                    float* __restrict__ out) {
  __shared__ float hm[128];
  __shared__ float red[128];
  int t = threadIdx.x;
  hm[t] = hsum[t] * (1.0f / (float)N_L);
  __syncthreads();
  float acc = b1[t];
  for (int k = 0; k < 128; ++k) acc = fmaf(hm[k], w1[k * 128 + t], acc);
  red[t] = fmaxf(acc, 0.f) * w2[t];
  for (int off = 64; off > 0; off >>= 1) {
    __syncthreads();
    if (t < off) red[t] += red[t + off];
  }
  __syncthreads();
  if (t == 0) out[0] = red[0] + b2[0];
}

__global__ __launch_bounds__(64) void mask_kernel(const float* __restrict__ lp,
                                                  float* __restrict__ out) {
  int i = threadIdx.x;
  if (i < L_H) out[i] = (lp[i] > 0.5f) ? 1.0f : 0.0f;
}

// ---------------- driver ----------------

extern "C" void kernel_launch(void* const* d_in, const int* in_sizes, int n_in,
                              void* d_out, int out_size, void* d_ws, size_t ws_size,
                              hipStream_t stream) {
  const float* x      = (const float*)d_in[0];
  const int*   ei     = (const int*)d_in[1];
  const float* head_x = (const float*)d_in[2];
  const int*   hei    = (const int*)d_in[3];
  const float* enc_w1 = (const float*)d_in[4];
  const float* enc_b1 = (const float*)d_in[5];
  const float* enc_w2 = (const float*)d_in[6];
  const float* enc_b2 = (const float*)d_in[7];
  const float* gnn_w1 = (const float*)d_in[8];
  const float* gnn_b1 = (const float*)d_in[9];
  const float* gnn_w2 = (const float*)d_in[10];
  const float* gnn_b2 = (const float*)d_in[11];
  const float* lp_w1  = (const float*)d_in[12];
  const float* lp_b1  = (const float*)d_in[13];
  const float* lp_w2  = (const float*)d_in[14];
  const float* lp_b2  = (const float*)d_in[15];
  const float* hp_w1  = (const float*)d_in[16];
  const float* hp_b1  = (const float*)d_in[17];
  const float* hp_w2  = (const float*)d_in[18];
  const float* hp_b2  = (const float*)d_in[19];
  const float* v_w1   = (const float*)d_in[20];
  const float* v_b1   = (const float*)d_in[21];
  const float* v_w2   = (const float*)d_in[22];
  const float* v_b2   = (const float*)d_in[23];
  float* out = (float*)d_out;

  // workspace layout (~116 MB)
  float* wsf = (float*)d_ws;
  float* A_l = wsf;                  // 40000*128
  float* B_l = A_l + 5120000;        // 40000*128
  float* A_h = B_l + 5120000;        // 65536*128
  float* B_h = A_h + 8388608;        // 65536*128
  float* dinv_l = B_h + 8388608;     // 40000
  float* dinv_h = dinv_l + 40000;    // 65536
  float* hsum   = dinv_h + 65536;    // 128
  int* ip       = (int*)(hsum + 128);
  int* indeg_l  = ip;  ip += 40000;
  int* rowptr_l = ip;  ip += 40064;
  int* rowpos_l = ip;  ip += 40000;
  int* col_l    = ip;  ip += 640000;
  int* indeg_h  = ip;  ip += 65536;
  int* rowptr_h = ip;  ip += 65600;
  int* rowpos_h = ip;  ip += 65536;
  int* col_h    = ip;  ip += 1048576;
  int* bsum_l   = ip;  ip += 64;
  int* bsum_h   = ip;  ip += 128;

  const int OUT_LP = 0, OUT_HP = N_L, OUT_MASK = N_L + N_HT, OUT_SV = N_L + N_HT + L_H;

  // ---- CSR + dinv build (both graphs) ----
  hipMemsetAsync(indeg_l, 0, N_L * sizeof(int), stream);
  hipMemsetAsync(indeg_h, 0, N_HT * sizeof(int), stream);
  hipMemsetAsync(hsum, 0, 128 * sizeof(float), stream);

  count_deg_l<<<E_L / 256, 256, 0, stream>>>(ei, indeg_l);
  count_deg_h<<<E_HT / 256, 256, 0, stream>>>(hei, indeg_h);
  dinv_kernel<<<(N_L + 255) / 256, 256, 0, stream>>>(indeg_l, dinv_l, N_L);
  dinv_kernel<<<N_HT / 256, 256, 0, stream>>>(indeg_h, dinv_h, N_HT);

  scan_block<<<40, 1024, 0, stream>>>(indeg_l, N_L, rowptr_l, bsum_l);
  scan_top<<<1, 64, 0, stream>>>(bsum_l, 40);
  scan_fix<<<(N_L + 256) / 256, 256, 0, stream>>>(rowptr_l, bsum_l, N_L, 40, rowpos_l);
  fill_csr_l<<<E_L / 256, 256, 0, stream>>>(ei, rowpos_l, col_l);

  scan_block<<<64, 1024, 0, stream>>>(indeg_h, N_HT, rowptr_h, bsum_h);
  scan_top<<<1, 64, 0, stream>>>(bsum_h, 64);
  scan_fix<<<(N_HT + 256) / 256, 256, 0, stream>>>(rowptr_h, bsum_h, N_HT, 64, rowpos_h);
  fill_csr_h<<<E_HT / 256, 256, 0, stream>>>(hei, rowpos_h, col_h);

  // ---- layer graph ----
  mm_kernel<256, true, true><<<N_L / 64, 256, 0, stream>>>(x, enc_w1, enc_b1, A_l, N_L);
  mm_kernel<128, true, true><<<N_L / 64, 256, 0, stream>>>(A_l, enc_w2, enc_b2, B_l, N_L);
  mm_kernel<128, false, false><<<N_L / 64, 256, 0, stream>>>(B_l, gnn_w1, nullptr, A_l, N_L);
  agg_kernel<<<N_L / 4, 256, 0, stream>>>(A_l, dinv_l, rowptr_l, col_l, gnn_b1, B_l, N_L);
  mm_kernel<128, false, false><<<N_L / 64, 256, 0, stream>>>(B_l, gnn_w2, nullptr, A_l, N_L);
  agg_kernel<<<N_L / 4, 256, 0, stream>>>(A_l, dinv_l, rowptr_l, col_l, gnn_b2, B_l, N_L);

  // layer policy
  mm_kernel<128, true, true><<<N_L / 64, 256, 0, stream>>>(B_l, lp_w1, lp_b1, A_l, N_L);
  prob_kernel<<<N_L / 4, 256, 0, stream>>>(A_l, lp_w2, lp_b2, out + OUT_LP, N_L);

  // value
  colsum_kernel<<<(N_L + 127) / 128, 128, 0, stream>>>(B_l, hsum, N_L);
  value_kernel<<<1, 128, 0, stream>>>(hsum, v_w1, v_b1, v_w2, v_b2, out + OUT_SV);

  // ---- head graphs (batched, node ids offset by l*8192) ----
  mm_kernel<256, true, true><<<N_HT / 64, 256, 0, stream>>>(head_x, enc_w1, enc_b1, A_h, N_HT);
  mm_kernel<128, true, true><<<N_HT / 64, 256, 0, stream>>>(A_h, enc_w2, enc_b2, B_h, N_HT);
  mm_kernel<128, false, false><<<N_HT / 64, 256, 0, stream>>>(B_h, gnn_w1, nullptr, A_h, N_HT);
  agg_kernel<<<N_HT / 4, 256, 0, stream>>>(A_h, dinv_h, rowptr_h, col_h, gnn_b1, B_h, N_HT);
  mm_kernel<128, false, false><<<N_HT / 64, 256, 0, stream>>>(B_h, gnn_w2, nullptr, A_h, N_HT);
  agg_kernel<<<N_HT / 4, 256, 0, stream>>>(A_h, dinv_h, rowptr_h, col_h, gnn_b2, B_h, N_HT);

  mm_kernel<128, true, true><<<N_HT / 64, 256, 0, stream>>>(B_h, hp_w1, hp_b1, A_h, N_HT);
  prob_kernel<<<N_HT / 4, 256, 0, stream>>>(A_h, hp_w2, hp_b2, out + OUT_HP, N_HT);

  // mask (reads layer_probs already in d_out)
  mask_kernel<<<1, 64, 0, stream>>>(out + OUT_LP, out + OUT_MASK);
}

// Round 2
// 602.874 us; speedup vs baseline: 1.2679x; 1.2679x over previous
//
#include <hip/hip_runtime.h>
#include <math.h>

// PruningAgent r1: all matmuls -> MFMA (16x16x32 bf16) with split-bf16 (hi+lo)
// for fp32-equivalent precision (3 MFMAs per product term). Weights pre-split
// + transposed once. Activations flow as split-bf16 between matmuls; GCN
// aggregation consumes fp32 (post gnn-mm) and emits split-bf16.

typedef unsigned short ushort_t;
using short8 = __attribute__((ext_vector_type(8))) short;
using f32x4  = __attribute__((ext_vector_type(4))) float;

constexpr int N_L  = 40000;
constexpr int E_L  = 640000;
constexpr int H_   = 128;
constexpr int L_H  = 8;
constexpr int N_H1 = 8192;
constexpr int E_H1 = 131072;
constexpr int N_HT = 65536;    // 8*8192
constexpr int E_HT = 1048576;  // 8*131072
constexpr int NLP  = 40064;    // layer rows padded to 128
constexpr int R_T  = 105600;   // NLP + N_HT (combined row space)
constexpr int HBASE = 40064;   // head rows start here

// ---------------- numeric helpers ----------------

__device__ __forceinline__ unsigned short bf16_rne(float f) {
  unsigned u = __float_as_uint(f);
  unsigned r = u + 0x7FFFu + ((u >> 16) & 1u);
  return (unsigned short)(r >> 16);
}
__device__ __forceinline__ float bfhi_f(unsigned short h) {
  return __uint_as_float((unsigned)h << 16);
}
__device__ __forceinline__ void split2(float f, unsigned short& h, unsigned short& l) {
  h = bf16_rne(f);
  l = bf16_rne(f - bfhi_f(h));
}

__device__ __forceinline__ void gload16(const void* g, void* l) {
  __builtin_amdgcn_global_load_lds((__attribute__((address_space(1))) void*)(g),
                                   (__attribute__((address_space(3))) void*)(l),
                                   16, 0, 0);
}

// ---------------- degree / CSR build ----------------

__global__ __launch_bounds__(256) void count_deg_l(const int* __restrict__ ei,
                                                   int* __restrict__ indeg) {
  int i = blockIdx.x * 256 + threadIdx.x;
  if (i < E_L) atomicAdd(&indeg[ei[E_L + i]], 1);
}

__global__ __launch_bounds__(256) void count_deg_h(const int* __restrict__ hei,
                                                   int* __restrict__ indeg) {
  int i = blockIdx.x * 256 + threadIdx.x;
  if (i < E_HT) {
    int l = i >> 17, e = i & (E_H1 - 1);
    atomicAdd(&indeg[l * N_H1 + hei[l * 2 * E_H1 + E_H1 + e]], 1);
  }
}

__global__ __launch_bounds__(256) void dinv_kernel(const int* __restrict__ indeg,
                                                   float* __restrict__ dinv, int n) {
  int i = blockIdx.x * 256 + threadIdx.x;
  if (i < n) dinv[i] = 1.0f / sqrtf((float)(indeg[i] + 1));
}

__global__ __launch_bounds__(1024) void scan_block(const int* __restrict__ in, int n,
                                                   int* __restrict__ out,
                                                   int* __restrict__ bsum) {
  __shared__ int s[1024];
  int t = threadIdx.x;
  int i = blockIdx.x * 1024 + t;
  int v = (i < n) ? in[i] : 0;
  s[t] = v;
  __syncthreads();
  for (int off = 1; off < 1024; off <<= 1) {
    int x = (t >= off) ? s[t - off] : 0;
    __syncthreads();
    s[t] += x;
    __syncthreads();
  }
  if (i < n) out[i] = s[t] - v;
  if (t == 1023) bsum[blockIdx.x] = s[t];
}

__global__ __launch_bounds__(64) void scan_top(int* __restrict__ bsum, int nb) {
  int lane = threadIdx.x;
  int v = (lane < nb) ? bsum[lane] : 0;
  int incl = v;
  for (int off = 1; off < 64; off <<= 1) {
    int x = __shfl_up(incl, off);
    if (lane >= off) incl += x;
  }
  int total = __shfl(incl, 63);
  if (lane < nb) bsum[lane] = incl - v;
  if (lane == 0) bsum[nb] = total;
}

__global__ __launch_bounds__(256) void scan_fix(int* __restrict__ rowptr,
                                                const int* __restrict__ bsum,
                                                int n, int nb,
                                                int* __restrict__ rowpos) {
  int i = blockIdx.x * 256 + threadIdx.x;
  if (i < n) {
    int v = rowptr[i] + bsum[i >> 10];
    rowptr[i] = v;
    rowpos[i] = v;
  } else if (i == n) {
    rowptr[n] = bsum[nb];
  }
}

__global__ __launch_bounds__(256) void fill_csr_l(const int* __restrict__ ei,
                                                  int* __restrict__ rowpos,
                                                  int* __restrict__ col) {
  int i = blockIdx.x * 256 + threadIdx.x;
  if (i < E_L) {
    int dst = ei[E_L + i];
    int p = atomicAdd(&rowpos[dst], 1);
    col[p] = ei[i];  // global id == local id for layer graph
  }
}

__global__ __launch_bounds__(256) void fill_csr_h(const int* __restrict__ hei,
                                                  int* __restrict__ rowpos,
                                                  int* __restrict__ col) {
  int i = blockIdx.x * 256 + threadIdx.x;
  if (i < E_HT) {
    int l = i >> 17, e = i & (E_H1 - 1);
    int base = l * 2 * E_H1;
    int dst = l * N_H1 + hei[base + E_H1 + e];
    int src = l * N_H1 + hei[base + e];
    int p = atomicAdd(&rowpos[dst], 1);
    col[p] = HBASE + src;  // global row id
  }
}

// ---------------- weight pre-split (transposed) ----------------
// dst layout Wt[c][k], split into hi/lo ushort arrays. Offsets (elements):
// enc_w1:0 (K=256), enc_w2:32768, gnn_w1:49152, gnn_w2:65536, lp_w1:81920, hp_w1:98304

__global__ __launch_bounds__(256) void conv_weights(
    const float* __restrict__ w0, const float* __restrict__ w1,
    const float* __restrict__ w2, const float* __restrict__ w3,
    const float* __restrict__ w4, const float* __restrict__ w5,
    unsigned short* __restrict__ th, unsigned short* __restrict__ tl) {
  int t = blockIdx.x * 256 + threadIdx.x;
  const float* src; int K, dstoff, idx;
  if (t < 32768) { src = w0; K = 256; dstoff = 0; idx = t; }
  else {
    int s = (t - 32768) >> 14;
    idx = (t - 32768) & 16383;
    K = 128;
    dstoff = 32768 + s * 16384;
    src = s == 0 ? w1 : s == 1 ? w2 : s == 2 ? w3 : s == 3 ? w4 : w5;
  }
  int k = idx >> 7, c = idx & 127;
  unsigned short h_, l_;
  split2(src[idx], h_, l_);
  th[dstoff + c * K + k] = h_;
  tl[dstoff + c * K + k] = l_;
}

// ---------------- MFMA matmul ----------------
// C[M,128] = act(A[M,K] @ W[K,128] + b), A as split-bf16 (or fp32 w/ CONV),
// W as pre-transposed split-bf16 Wt[128][K]. 128-row tile, 4 waves, KC=64.
// LDS XOR-swizzle: 16B unit x of row r stored at unit r*8 + (x ^ (r&7)).

template <int K, bool CONV, bool RELU, bool BIAS, bool SPLITOUT>
__global__ __launch_bounds__(256) void mm_mfma(
    const float* __restrict__ Af,
    const unsigned short* __restrict__ Ah, const unsigned short* __restrict__ Al,
    const unsigned short* __restrict__ Wth, const unsigned short* __restrict__ Wtl,
    const float* __restrict__ bias,
    float* __restrict__ Cf, unsigned short* __restrict__ Ch,
    unsigned short* __restrict__ Cl, int Mreal) {
  __shared__ __align__(16) char lds[65536];
  char* As_h = lds;
  char* As_l = lds + 16384;
  char* Ws_h = lds + 32768;
  char* Ws_l = lds + 49152;

  const int tid = threadIdx.x;
  const int lane = tid & 63;
  const int wv = tid >> 6;
  const int g = lane >> 4;
  const int li = lane & 15;
  const int row0 = blockIdx.x * 128;

  f32x4 acc[2][8];
#pragma unroll
  for (int m = 0; m < 2; ++m)
#pragma unroll
    for (int j = 0; j < 8; ++j) acc[m][j] = f32x4{0.f, 0.f, 0.f, 0.f};

  const int rsub = lane >> 3;                   // row-within-8 for staging
  const int xr = (lane & 7) ^ ((lane >> 3) & 7); // pre-swizzled source unit

  for (int kc = 0; kc < K; kc += 64) {
    __syncthreads();
    // stage W chunk (both splits): 16 KB each, 4 issues/wave
#pragma unroll
    for (int j = 0; j < 4; ++j) {
      int q = wv * 4 + j;
      int c = q * 8 + rsub;
      size_t gb = ((size_t)c * K + kc) * 2 + (size_t)xr * 16;
      gload16((const char*)Wth + gb, Ws_h + q * 1024);
      gload16((const char*)Wtl + gb, Ws_l + q * 1024);
    }
    if constexpr (!CONV) {
#pragma unroll
      for (int j = 0; j < 4; ++j) {
        int q = wv * 4 + j;
        int r = q * 8 + rsub;
        size_t gb = ((size_t)(row0 + r) * K + kc) * 2 + (size_t)xr * 16;
        gload16((const char*)Ah + gb, As_h + q * 1024);
        gload16((const char*)Al + gb, As_l + q * 1024);
      }
    } else {
      // fp32 A -> convert to split bf16, swizzled ds_write
      int r = tid >> 1, hf = tid & 1;
      int grow = min(row0 + r, Mreal - 1);
      const float* src = Af + (size_t)grow * K + kc + hf * 32;
#pragma unroll
      for (int i = 0; i < 4; ++i) {
        float4 a = ((const float4*)src)[2 * i];
        float4 b = ((const float4*)src)[2 * i + 1];
        float f[8] = {a.x, a.y, a.z, a.w, b.x, b.y, b.z, b.w};
        short8 vh, vl;
#pragma unroll
        for (int e = 0; e < 8; ++e) {
          unsigned short h_, l_;
          split2(f[e], h_, l_);
          vh[e] = (short)h_;
          vl[e] = (short)l_;
        }
        int x = hf * 4 + i;
        int u = r * 8 + (x ^ (r & 7));
        *(short8*)(As_h + u * 16) = vh;
        *(short8*)(As_l + u * 16) = vl;
      }
    }
    __syncthreads();

    // A fragments: rows wv*32 + m*16 + li, k = ks*32 + 8g + e
    short8 fa_h[2][2], fa_l[2][2];
#pragma unroll
    for (int m = 0; m < 2; ++m)
#pragma unroll
      for (int ks = 0; ks < 2; ++ks) {
        int row = wv * 32 + m * 16 + li;
        int off = row * 128 + ks * 64 + g * 16;
        off ^= (row & 7) << 4;
        fa_h[m][ks] = *(const short8*)(As_h + off);
        fa_l[m][ks] = *(const short8*)(As_l + off);
      }
#pragma unroll
    for (int nh = 0; nh < 2; ++nh) {
      short8 fb_h[4][2], fb_l[4][2];
#pragma unroll
      for (int n = 0; n < 4; ++n)
#pragma unroll
        for (int ks = 0; ks < 2; ++ks) {
          int c = nh * 64 + n * 16 + li;
          int off = c * 128 + ks * 64 + g * 16;
          off ^= (c & 7) << 4;
          fb_h[n][ks] = *(const short8*)(Ws_h + off);
          fb_l[n][ks] = *(const short8*)(Ws_l + off);
        }
#pragma unroll
      for (int m = 0; m < 2; ++m)
#pragma unroll
        for (int n = 0; n < 4; ++n)
#pragma unroll
          for (int ks = 0; ks < 2; ++ks) {
            f32x4 a_ = acc[m][nh * 4 + n];
            a_ = __builtin_amdgcn_mfma_f32_16x16x32_bf16(fa_h[m][ks], fb_h[n][ks], a_, 0, 0, 0);
            a_ = __builtin_amdgcn_mfma_f32_16x16x32_bf16(fa_h[m][ks], fb_l[n][ks], a_, 0, 0, 0);
            a_ = __builtin_amdgcn_mfma_f32_16x16x32_bf16(fa_l[m][ks], fb_h[n][ks], a_, 0, 0, 0);
            acc[m][nh * 4 + n] = a_;
          }
    }
  }

  // epilogue: D row = (lane>>4)*4 + reg, col = lane&15 (m89-verified)
#pragma unroll
  for (int m = 0; m < 2; ++m)
#pragma unroll
    for (int j = 0; j < 8; ++j) {
      int c = j * 16 + li;
      float bj = BIAS ? bias[c] : 0.f;
#pragma unroll
      for (int r = 0; r < 4; ++r) {
        int rowg = row0 + wv * 32 + m * 16 + g * 4 + r;
        float o = acc[m][j][r] + bj;
        if (RELU) o = fmaxf(o, 0.f);
        size_t idx = (size_t)rowg * 128 + c;
        if constexpr (SPLITOUT) {
          unsigned short h_, l_;
          split2(o, h_, l_);
          Ch[idx] = h_;
          Cl[idx] = l_;
        } else {
          Cf[idx] = o;
        }
      }
    }
}

// ---------------- GCN aggregation (gather), split-bf16 out ----------------

__global__ __launch_bounds__(256) void agg_split(const float* __restrict__ Hin,
                                                 const float* __restrict__ dinvg,
                                                 const int* __restrict__ rowptr,
                                                 const int* __restrict__ col,
                                                 const float* __restrict__ bias,
                                                 unsigned short* __restrict__ Oh,
                                                 unsigned short* __restrict__ Ol,
                                                 int n, int base) {
  int v = blockIdx.x * 4 + (threadIdx.x >> 6);
  int lane = threadIdx.x & 63;
  int gnode = base + v;
  float2 acc;
  acc.x = 0.f;
  acc.y = 0.f;
  if (v < n) {
    const float2* H2 = (const float2*)Hin;
    float dv = dinvg[gnode];
    float2 h = H2[(size_t)gnode * 64 + lane];
    acc.x = h.x * dv * dv;
    acc.y = h.y * dv * dv;
    int e = rowptr[v], e1 = rowptr[v + 1];
    for (; e + 4 <= e1; e += 4) {
      int u0 = col[e], u1 = col[e + 1], u2 = col[e + 2], u3 = col[e + 3];
      float c0 = dinvg[u0] * dv, c1 = dinvg[u1] * dv;
      float c2 = dinvg[u2] * dv, c3 = dinvg[u3] * dv;
      float2 x0 = H2[(size_t)u0 * 64 + lane];
      float2 x1 = H2[(size_t)u1 * 64 + lane];
      float2 x2 = H2[(size_t)u2 * 64 + lane];
      float2 x3 = H2[(size_t)u3 * 64 + lane];
      acc.x += x0.x * c0 + x1.x * c1 + x2.x * c2 + x3.x * c3;
      acc.y += x0.y * c0 + x1.y * c1 + x2.y * c2 + x3.y * c3;
    }
    for (; e < e1; ++e) {
      int u = col[e];
      float c = dinvg[u] * dv;
      float2 x = H2[(size_t)u * 64 + lane];
      acc.x += x.x * c;
      acc.y += x.y * c;
    }
    float2 b2 = ((const float2*)bias)[lane];
    acc.x = fmaxf(acc.x + b2.x, 0.f);
    acc.y = fmaxf(acc.y + b2.y, 0.f);
  }
  unsigned short hx, lx, hy, ly;
  split2(acc.x, hx, lx);
  split2(acc.y, hy, ly);
  ushort2 th, tl;
  th.x = hx; th.y = hy;
  tl.x = lx; tl.y = ly;
  ((ushort2*)Oh)[(size_t)gnode * 64 + lane] = th;
  ((ushort2*)Ol)[(size_t)gnode * 64 + lane] = tl;
}

// ---------------- heads ----------------

__global__ __launch_bounds__(256) void prob_kernel(const float* __restrict__ Hrelu,
                                                   const float* __restrict__ w2,
                                                   const float* __restrict__ b2,
                                                   float* __restrict__ out, int n) {
  int r = blockIdx.x * 4 + (threadIdx.x >> 6);
  if (r >= n) return;
  int lane = threadIdx.x & 63;
  float2 h = ((const float2*)Hrelu)[(size_t)r * 64 + lane];
  float2 w = ((const float2*)w2)[lane];
  float p = h.x * w.x + h.y * w.y;
  for (int off = 32; off; off >>= 1) p += __shfl_down(p, off);
  if (lane == 0) out[r] = 1.0f / (1.0f + expf(-(p + b2[0])));
}

__global__ __launch_bounds__(128) void colsum_split(const unsigned short* __restrict__ Hh,
                                                    const unsigned short* __restrict__ Hl,
                                                    float* __restrict__ hsum, int n) {
  int f = threadIdx.x;
  int r0 = blockIdx.x * 128;
  int r1 = min(r0 + 128, n);
  float acc = 0.f;
  for (int r = r0; r < r1; ++r) {
    size_t idx = (size_t)r * 128 + f;
    acc += bfhi_f(Hh[idx]) + bfhi_f(Hl[idx]);
  }
  atomicAdd(&hsum[f], acc);
}

__global__ __launch_bounds__(128) void value_kernel(const float* __restrict__ hsum,
                                                    const float* __restrict__ w1,
                                                    const float* __restrict__ b1,
                                                    const float* __restrict__ w2,
                                                    const float* __restrict__ b2,
                                                    float* __restrict__ out) {
  __shared__ float hm[128];
  __shared__ float red[128];
  int t = threadIdx.x;
  hm[t] = hsum[t] * (1.0f / (float)N_L);
  __syncthreads();
  float acc = b1[t];
  for (int k = 0; k < 128; ++k) acc = fmaf(hm[k], w1[k * 128 + t], acc);
  red[t] = fmaxf(acc, 0.f) * w2[t];
  for (int off = 64; off > 0; off >>= 1) {
    __syncthreads();
    if (t < off) red[t] += red[t + off];
  }
  __syncthreads();
  if (t == 0) out[0] = red[0] + b2[0];
}

__global__ __launch_bounds__(64) void mask_kernel(const float* __restrict__ lp,
                                                  float* __restrict__ out) {
  int i = threadIdx.x;
  if (i < L_H) out[i] = (lp[i] > 0.5f) ? 1.0f : 0.0f;
}

// ---------------- driver ----------------

extern "C" void kernel_launch(void* const* d_in, const int* in_sizes, int n_in,
                              void* d_out, int out_size, void* d_ws, size_t ws_size,
                              hipStream_t stream) {
  const float* x      = (const float*)d_in[0];
  const int*   ei     = (const int*)d_in[1];
  const float* head_x = (const float*)d_in[2];
  const int*   hei    = (const int*)d_in[3];
  const float* enc_w1 = (const float*)d_in[4];
  const float* enc_b1 = (const float*)d_in[5];
  const float* enc_w2 = (const float*)d_in[6];
  const float* enc_b2 = (const float*)d_in[7];
  const float* gnn_w1 = (const float*)d_in[8];
  const float* gnn_b1 = (const float*)d_in[9];
  const float* gnn_w2 = (const float*)d_in[10];
  const float* gnn_b2 = (const float*)d_in[11];
  const float* lp_w1  = (const float*)d_in[12];
  const float* lp_b1  = (const float*)d_in[13];
  const float* lp_w2  = (const float*)d_in[14];
  const float* lp_b2  = (const float*)d_in[15];
  const float* hp_w1  = (const float*)d_in[16];
  const float* hp_b1  = (const float*)d_in[17];
  const float* hp_w2  = (const float*)d_in[18];
  const float* hp_b2  = (const float*)d_in[19];
  const float* v_w1   = (const float*)d_in[20];
  const float* v_b1   = (const float*)d_in[21];
  const float* v_w2   = (const float*)d_in[22];
  const float* v_b2   = (const float*)d_in[23];
  float* out = (float*)d_out;

  // ---- workspace layout ----
  const size_t ELE = (size_t)R_T * 128;          // 13,516,800
  char* base = (char*)d_ws;
  float* SAf = (float*)base;                      // SLOT_A (f32 view)
  unsigned short* SAh = (unsigned short*)base;    // SLOT_A (split view)
  unsigned short* SAl = SAh + ELE;
  char* baseB = base + ELE * 4;
  float* SBf = (float*)baseB;
  unsigned short* SBh = (unsigned short*)baseB;
  unsigned short* SBl = SBh + ELE;
  unsigned short* WTh = (unsigned short*)(baseB + ELE * 4);  // 114688 elems
  unsigned short* WTl = WTh + 114688;
  float* dinv_g = (float*)(WTl + 114688);         // [R_T]
  float* hsum   = dinv_g + R_T;                   // [128]
  int* ip       = (int*)(hsum + 128);
  int* indeg_l  = ip;  ip += 40000;   // doubles as rowpos_l
  int* rowptr_l = ip;  ip += 40065;
  int* col_l    = ip;  ip += 640000;
  int* indeg_h  = ip;  ip += 65536;   // doubles as rowpos_h
  int* rowptr_h = ip;  ip += 65537;
  int* col_h    = ip;  ip += 1048576;
  int* bsum_l   = ip;  ip += 48;
  int* bsum_h   = ip;  ip += 72;

  // Wt element offsets
  const int WT_ENC1 = 0, WT_ENC2 = 32768, WT_G1 = 49152, WT_G2 = 65536,
            WT_LP = 81920, WT_HP = 98304;

  const int OUT_LP = 0, OUT_HP = N_L, OUT_MASK = N_L + N_HT, OUT_SV = N_L + N_HT + L_H;

  // ---- CSR + dinv + weight split ----
  hipMemsetAsync(indeg_l, 0, 40000 * sizeof(int), stream);
  hipMemsetAsync(indeg_h, 0, (size_t)N_HT * sizeof(int), stream);
  hipMemsetAsync(hsum, 0, 128 * sizeof(float), stream);

  conv_weights<<<448, 256, 0, stream>>>(enc_w1, enc_w2, gnn_w1, gnn_w2, lp_w1, hp_w1,
                                        WTh, WTl);

  count_deg_l<<<E_L / 256, 256, 0, stream>>>(ei, indeg_l);
  count_deg_h<<<E_HT / 256, 256, 0, stream>>>(hei, indeg_h);
  dinv_kernel<<<(N_L + 255) / 256, 256, 0, stream>>>(indeg_l, dinv_g, N_L);
  dinv_kernel<<<N_HT / 256, 256, 0, stream>>>(indeg_h, dinv_g + HBASE, N_HT);

  scan_block<<<40, 1024, 0, stream>>>(indeg_l, N_L, rowptr_l, bsum_l);
  scan_top<<<1, 64, 0, stream>>>(bsum_l, 40);
  scan_fix<<<(N_L + 256) / 256, 256, 0, stream>>>(rowptr_l, bsum_l, N_L, 40, indeg_l);
  fill_csr_l<<<E_L / 256, 256, 0, stream>>>(ei, indeg_l, col_l);

  scan_block<<<64, 1024, 0, stream>>>(indeg_h, N_HT, rowptr_h, bsum_h);
  scan_top<<<1, 64, 0, stream>>>(bsum_h, 64);
  scan_fix<<<(N_HT + 256) / 256, 256, 0, stream>>>(rowptr_h, bsum_h, N_HT, 64, indeg_h);
  fill_csr_h<<<E_HT / 256, 256, 0, stream>>>(hei, indeg_h, col_h);

  // ---- encoder (enc1: fp32 in, CONV; layer + head into combined split buf) ----
  mm_mfma<256, true, true, true, true><<<NLP / 128, 256, 0, stream>>>(
      x, nullptr, nullptr, WTh + WT_ENC1, WTl + WT_ENC1, enc_b1,
      nullptr, SAh, SAl, N_L);
  mm_mfma<256, true, true, true, true><<<N_HT / 128, 256, 0, stream>>>(
      head_x, nullptr, nullptr, WTh + WT_ENC1, WTl + WT_ENC1, enc_b1,
      nullptr, SAh + (size_t)HBASE * 128, SAl + (size_t)HBASE * 128, N_HT);

  mm_mfma<128, false, true, true, true><<<R_T / 128, 256, 0, stream>>>(
      nullptr, SAh, SAl, WTh + WT_ENC2, WTl + WT_ENC2, enc_b2,
      nullptr, SBh, SBl, R_T);

  // ---- GCN layer 1 ----
  mm_mfma<128, false, false, false, false><<<R_T / 128, 256, 0, stream>>>(
      nullptr, SBh, SBl, WTh + WT_G1, WTl + WT_G1, nullptr,
      SAf, nullptr, nullptr, R_T);
  agg_split<<<NLP / 4, 256, 0, stream>>>(SAf, dinv_g, rowptr_l, col_l, gnn_b1,
                                         SBh, SBl, N_L, 0);
  agg_split<<<N_HT / 4, 256, 0, stream>>>(SAf, dinv_g, rowptr_h, col_h, gnn_b1,
                                          SBh, SBl, N_HT, HBASE);

  // ---- GCN layer 2 ----
  mm_mfma<128, false, false, false, false><<<R_T / 128, 256, 0, stream>>>(
      nullptr, SBh, SBl, WTh + WT_G2, WTl + WT_G2, nullptr,
      SAf, nullptr, nullptr, R_T);
  agg_split<<<NLP / 4, 256, 0, stream>>>(SAf, dinv_g, rowptr_l, col_l, gnn_b2,
                                         SBh, SBl, N_L, 0);
  agg_split<<<N_HT / 4, 256, 0, stream>>>(SAf, dinv_g, rowptr_h, col_h, gnn_b2,
                                          SBh, SBl, N_HT, HBASE);

  // ---- layer policy + value ----
  mm_mfma<128, false, true, true, false><<<NLP / 128, 256, 0, stream>>>(
      nullptr, SBh, SBl, WTh + WT_LP, WTl + WT_LP, lp_b1,
      SAf, nullptr, nullptr, NLP);
  prob_kernel<<<N_L / 4, 256, 0, stream>>>(SAf, lp_w2, lp_b2, out + OUT_LP, N_L);

  colsum_split<<<(N_L + 127) / 128, 128, 0, stream>>>(SBh, SBl, hsum, N_L);
  value_kernel<<<1, 128, 0, stream>>>(hsum, v_w1, v_b1, v_w2, v_b2, out + OUT_SV);

  // ---- head policy ----
  mm_mfma<128, false, true, true, false><<<N_HT / 128, 256, 0, stream>>>(
      nullptr, SBh + (size_t)HBASE * 128, SBl + (size_t)HBASE * 128,
      WTh + WT_HP, WTl + WT_HP, hp_b1,
      SAf, nullptr, nullptr, N_HT);
  prob_kernel<<<N_HT / 4, 256, 0, stream>>>(SAf, hp_w2, hp_b2, out + OUT_HP, N_HT);

  // ---- mask ----
  mask_kernel<<<1, 64, 0, stream>>>(out + OUT_LP, out + OUT_MASK);
}